// Round 5
// baseline (550.499 us; speedup 1.0000x reference)
//
#include <hip/hip_runtime.h>

// DenseNet ValueModel, bf16 3-term split MFMA, v4.
// vs v3 (535us, MfmaUtil 21%, latency-bound): K-split 4 x N-split 2 (merged
// single reduction, 2 barriers/layer instead of 4), 2-deep software-pipelined
// B prefetch from global (L2-hot), division-free reduce with conflict-free
// slab layout. Pre-kernel + all fragment layouts identical to the PASSING v3.

#define IN 16
#define KJ 50
#define NL 25
#define FW 1266
#define TR 24
#define NB 1366          // ceil(32768/24); last block: 8 live rows
#define BTOT 32768
#define XSTR 1288        // u16/row; 2576B row stride
#define NTHREADS 512
#define XLO_OFF 61824    // 24*1288*2
#define SLAB_OFF 123648  // 2*61824
#define LDS_BYTES 148224 // + 4*24*64*4 slab; A-row-overrun (rows 24..31) reads stay in-bounds
#define CHUNK_STRIDE 3200
#define TOTAL_CHUNKS 973

typedef __attribute__((ext_vector_type(8))) short bf16x8;
typedef __attribute__((ext_vector_type(16))) float f32x16;

__device__ __forceinline__ unsigned short bf16_hi(float x, float* hif) {
    unsigned u = __float_as_uint(x);
    unsigned h = (u + 0x8000u) >> 16;
    *hif = __uint_as_float(h << 16);
    return (unsigned short)h;
}
__device__ __forceinline__ unsigned short bf16_rnd(float x) {
    return (unsigned short)((__float_as_uint(x) + 0x8000u) >> 16);
}

// ---------------- pre-kernel: split + fragment W into d_ws (UNCHANGED, verified) ----
__device__ __forceinline__ void split8(const float* __restrict__ rowp, int kb, int width,
                                       unsigned hi[4], unsigned lo[4]) {
#pragma unroll
    for (int p = 0; p < 4; ++p) {
        unsigned h2[2], l2[2];
#pragma unroll
        for (int q = 0; q < 2; ++q) {
            int k = kb + p * 2 + q;
            float v = (k < width) ? rowp[k] : 0.f;
            float hif;
            unsigned short h = bf16_hi(v, &hif);
            h2[q] = h;
            l2[q] = bf16_rnd(v - hif);
        }
        hi[p] = h2[0] | (h2[1] << 16);
        lo[p] = l2[0] | (l2[1] << 16);
    }
}

__global__ __launch_bounds__(64, 1) void split_w(const float* __restrict__ Ws,
                                                 char* __restrict__ wsbuf) {
    int rem = blockIdx.x, layer = 0;
    size_t off = 0;
    for (;;) {
        int c = (IN + KJ * layer + 15) >> 4;
        if (rem < c) break;
        rem -= c; off += (size_t)c * CHUNK_STRIDE; ++layer;
    }
    const int ci = rem, k0 = ci << 4, width = IN + KJ * layer;
    const float* Wl = Ws + (size_t)layer * KJ * FW;
    char* base = wsbuf + off + (size_t)ci * CHUNK_STRIDE;
    const int l = threadIdx.x, ll = l & 31, kh = l >> 5;
    const int kb = k0 + kh * 8;

    unsigned hi[4], lo[4];
    split8(Wl + (size_t)ll * FW, kb, width, hi, lo);          // n0: j = ll (< 50)
    *reinterpret_cast<uint4*>(base + l * 16)        = make_uint4(hi[0], hi[1], hi[2], hi[3]);
    *reinterpret_cast<uint4*>(base + 1024 + l * 16) = make_uint4(lo[0], lo[1], lo[2], lo[3]);
    if (ll < 18) {                                            // n1: j = 32+ll (<= 49), compacted
        split8(Wl + (size_t)(32 + ll) * FW, kb, width, hi, lo);
        *reinterpret_cast<uint4*>(base + 2048 + (kh * 18 + ll) * 16) = make_uint4(hi[0], hi[1], hi[2], hi[3]);
        *reinterpret_cast<uint4*>(base + 2624 + (kh * 18 + ll) * 16) = make_uint4(lo[0], lo[1], lo[2], lo[3]);
    }
}

// B-fragment load for chunk ci, n-tile n (wave-uniform n -> uniform branch)
__device__ __forceinline__ void loadB(const char* __restrict__ wb, int ci, int n,
                                      int l, int ll, int kh, bf16x8& bh, bf16x8& bl) {
    const char* cb = wb + (size_t)ci * CHUNK_STRIDE;
    if (n == 0) {
        bh = *(const bf16x8*)(cb + l * 16);
        bl = *(const bf16x8*)(cb + 1024 + l * 16);
    } else {
        bf16x8 z = {0, 0, 0, 0, 0, 0, 0, 0};
        bh = z; bl = z;
        if (ll < 18) {
            bh = *(const bf16x8*)(cb + 2048 + (kh * 18 + ll) * 16);
            bl = *(const bf16x8*)(cb + 2624 + (kh * 18 + ll) * 16);
        }
    }
}

// ---------------- main kernel ----------------
__global__ __launch_bounds__(NTHREADS, 1) void densenet_mfma(
    const float* __restrict__ state, const char* __restrict__ wsbuf,
    const float* __restrict__ bs,    const float* __restrict__ Wout,
    const float* __restrict__ bout,  float* __restrict__ out)
{
    __shared__ __align__(16) char lds[LDS_BYTES];
    unsigned short* xhi = (unsigned short*)lds;
    unsigned short* xlo = (unsigned short*)(lds + XLO_OFF);
    float* slab = (float*)(lds + SLAB_OFF);     // [kq 4][row 24][col 64] f32

    const int tid = threadIdx.x;
    const int w   = tid >> 6;
    const int l   = tid & 63;
    const int ll  = l & 31, kh = l >> 5;
    const int kq  = w & 3;          // K-chunk residue this wave owns
    const int n   = w >> 2;         // N-tile this wave owns
    const long row0 = (long)blockIdx.x * TR;

    // zero x planes (zero padding masks k-tails; rows beyond live batch stay 0)
    {
        unsigned* p = (unsigned*)lds;
        for (int i = tid; i < (XLO_OFF * 2) / 4; i += NTHREADS) p[i] = 0u;
    }
    __syncthreads();
    if (tid < TR * IN) {
        int r = tid >> 4, c = tid & 15;
        if (row0 + r < BTOT) {
            float v = state[(row0 + r) * IN + c];
            float hif;
            xhi[r * XSTR + c] = bf16_hi(v, &hif);
            xlo[r * XSTR + c] = bf16_rnd(v - hif);
        }
    }
    __syncthreads();   // x init visible to all waves

    int width = IN;
    size_t wofs = 0;
    for (int layer = 0; layer < NL; ++layer) {
        const int chunks = (width + 15) >> 4;
        const char* wb = wsbuf + wofs;

        f32x16 acc;
#pragma unroll
        for (int i = 0; i < 16; ++i) acc[i] = 0.f;

        // ---- compute: wave (kq,n) owns chunks ci%4==kq, 2-deep B prefetch ----
        bf16x8 h0 = {0,0,0,0,0,0,0,0}, l0v = h0, h1 = h0, l1v = h0;
        if (kq < chunks)     loadB(wb, kq,     n, l, ll, kh, h0, l0v);
        if (kq + 4 < chunks) loadB(wb, kq + 4, n, l, ll, kh, h1, l1v);
        for (int ci = kq; ci < chunks; ci += 8) {
            {
                const int kof = (ci << 4) + (kh << 3);
                bf16x8 ah = *(const bf16x8*)&xhi[ll * XSTR + kof];  // rows 24..31: in-bounds
                bf16x8 al = *(const bf16x8*)&xlo[ll * XSTR + kof];  // garbage -> dead acc regs
                acc = __builtin_amdgcn_mfma_f32_32x32x16_bf16(al, h0, acc, 0, 0, 0);
                acc = __builtin_amdgcn_mfma_f32_32x32x16_bf16(ah, l0v, acc, 0, 0, 0);
                acc = __builtin_amdgcn_mfma_f32_32x32x16_bf16(ah, h0, acc, 0, 0, 0);
            }
            if (ci + 8 < chunks) loadB(wb, ci + 8, n, l, ll, kh, h0, l0v);
            if (ci + 4 < chunks) {
                const int kof = ((ci + 4) << 4) + (kh << 3);
                bf16x8 ah = *(const bf16x8*)&xhi[ll * XSTR + kof];
                bf16x8 al = *(const bf16x8*)&xlo[ll * XSTR + kof];
                acc = __builtin_amdgcn_mfma_f32_32x32x16_bf16(al, h1, acc, 0, 0, 0);
                acc = __builtin_amdgcn_mfma_f32_32x32x16_bf16(ah, l1v, acc, 0, 0, 0);
                acc = __builtin_amdgcn_mfma_f32_32x32x16_bf16(ah, h1, acc, 0, 0, 0);
                if (ci + 12 < chunks) loadB(wb, ci + 12, n, l, ll, kh, h1, l1v);
            }
        }

        // ---- slab write: C rows 0..23 <-> acc regs 0..11 ----
        // C layout: col=l&31, row=(r&3)+8*(r>>2)+4*(l>>5); slab col = n*32+ll == final j
        {
            float* sl = slab + kq * 1536;
#pragma unroll
            for (int r = 0; r < 12; ++r) {
                int crow = (r & 3) + 8 * (r >> 2) + 4 * kh;
                sl[crow * 64 + n * 32 + ll] = acc[r];
            }
        }
        __syncthreads();   // (1) slab complete; all A-reads of this layer done

        // ---- merged reduce: 24 rows x 64 cols, j<50 live ----
#pragma unroll
        for (int it = 0; it < 3; ++it) {
            int idx = it * NTHREADS + tid;
            int row = idx >> 6, j = idx & 63;
            float s = slab[row * 64 + j] + slab[1536 + row * 64 + j]
                    + slab[3072 + row * 64 + j] + slab[4608 + row * 64 + j];
            if (j < KJ) {
                s += bs[layer * KJ + j];
                s = (s > 0.f) ? s : 0.01f * s;
                float hif;
                xhi[row * XSTR + width + j] = bf16_hi(s, &hif);
                xlo[row * XSTR + width + j] = bf16_rnd(s - hif);
            }
        }
        __syncthreads();   // (2) new x cols visible; slab free for next layer

        width += KJ;
        wofs += (size_t)chunks * CHUNK_STRIDE;
    }

    // epilogue: out[r] = x[r] . Wout + bout ; 3 rows/wave, 64-lane dot
#pragma unroll
    for (int rr = 0; rr < 3; ++rr) {
        const int row = w * 3 + rr;
        const long grow = row0 + row;
        float s = 0.f;
        for (int k = l; k < FW; k += 64) {
            float xv = __uint_as_float((unsigned)xhi[row * XSTR + k] << 16)
                     + __uint_as_float((unsigned)xlo[row * XSTR + k] << 16);
            s += xv * Wout[k];
        }
#pragma unroll
        for (int m = 32; m >= 1; m >>= 1) s += __shfl_xor(s, m, 64);
        if (l == 0 && grow < BTOT) out[grow] = s + bout[0];
    }
}

extern "C" void kernel_launch(void* const* d_in, const int* in_sizes, int n_in,
                              void* d_out, int out_size, void* d_ws, size_t ws_size,
                              hipStream_t stream) {
    const float* state = (const float*)d_in[0];
    const float* Ws    = (const float*)d_in[1];
    const float* bs    = (const float*)d_in[2];
    const float* Wout  = (const float*)d_in[3];
    const float* bout  = (const float*)d_in[4];
    float* out = (float*)d_out;
    char* wsbuf = (char*)d_ws;   // needs TOTAL_CHUNKS*CHUNK_STRIDE = 3,113,600 B

    split_w<<<dim3(TOTAL_CHUNKS), dim3(64), 0, stream>>>(Ws, wsbuf);
    densenet_mfma<<<dim3(NB), dim3(NTHREADS), 0, stream>>>(state, wsbuf, bs, Wout, bout, out);
}

// Round 7
// 512.314 us; speedup vs baseline: 1.0745x; 1.0745x over previous
//
#include <hip/hip_runtime.h>

// DenseNet ValueModel, bf16 3-term split MFMA, v5 (resubmit — round-6 broker timeout).
// vs v4 (550us, MfmaUtil 20%, VALU 34%): the acc dependency chain was serial
// (each MFMA waits ~32cyc on the previous). v5: 4 independent acc chains per
// wave (2-chunk ping-pong groups, chains (a0,a1)/(a2,a3) by group parity),
// register-named double-buffered B prefetch, hoisted A-row base, Wout+bias
// preloaded to LDS (epilogue/reduce off the global-latency path).
// Pre-kernel + all fragment layouts byte-identical to PASSING v3/v4.

#define IN 16
#define KJ 50
#define NL 25
#define FW 1266
#define TR 24
#define NB 1366          // ceil(32768/24); last block: 8 live rows
#define BTOT 32768
#define XSTR 1288        // u16/row
#define NTHREADS 512
#define XLO_OFF 61824    // 24*1288*2
#define SLAB_OFF 123648  // 2*61824
#define WOUT_OFF 148224  // + 4*24*64*4 slab
#define BIAS_OFF 153344  // + 1280 floats
#define LDS_BYTES 158464 // + 1250 floats bias (pad); <= 160KB, 1 block/CU
#define CHUNK_STRIDE 3200
#define TOTAL_CHUNKS 973

typedef __attribute__((ext_vector_type(8))) short bf16x8;
typedef __attribute__((ext_vector_type(16))) float f32x16;

__device__ __forceinline__ unsigned short bf16_hi(float x, float* hif) {
    unsigned u = __float_as_uint(x);
    unsigned h = (u + 0x8000u) >> 16;
    *hif = __uint_as_float(h << 16);
    return (unsigned short)h;
}
__device__ __forceinline__ unsigned short bf16_rnd(float x) {
    return (unsigned short)((__float_as_uint(x) + 0x8000u) >> 16);
}

// ---------------- pre-kernel: split + fragment W into d_ws (UNCHANGED, verified) ----
__device__ __forceinline__ void split8(const float* __restrict__ rowp, int kb, int width,
                                       unsigned hi[4], unsigned lo[4]) {
#pragma unroll
    for (int p = 0; p < 4; ++p) {
        unsigned h2[2], l2[2];
#pragma unroll
        for (int q = 0; q < 2; ++q) {
            int k = kb + p * 2 + q;
            float v = (k < width) ? rowp[k] : 0.f;
            float hif;
            unsigned short h = bf16_hi(v, &hif);
            h2[q] = h;
            l2[q] = bf16_rnd(v - hif);
        }
        hi[p] = h2[0] | (h2[1] << 16);
        lo[p] = l2[0] | (l2[1] << 16);
    }
}

__global__ __launch_bounds__(64, 1) void split_w(const float* __restrict__ Ws,
                                                 char* __restrict__ wsbuf) {
    int rem = blockIdx.x, layer = 0;
    size_t off = 0;
    for (;;) {
        int c = (IN + KJ * layer + 15) >> 4;
        if (rem < c) break;
        rem -= c; off += (size_t)c * CHUNK_STRIDE; ++layer;
    }
    const int ci = rem, k0 = ci << 4, width = IN + KJ * layer;
    const float* Wl = Ws + (size_t)layer * KJ * FW;
    char* base = wsbuf + off + (size_t)ci * CHUNK_STRIDE;
    const int l = threadIdx.x, ll = l & 31, kh = l >> 5;
    const int kb = k0 + kh * 8;

    unsigned hi[4], lo[4];
    split8(Wl + (size_t)ll * FW, kb, width, hi, lo);          // n0: j = ll (< 50)
    *reinterpret_cast<uint4*>(base + l * 16)        = make_uint4(hi[0], hi[1], hi[2], hi[3]);
    *reinterpret_cast<uint4*>(base + 1024 + l * 16) = make_uint4(lo[0], lo[1], lo[2], lo[3]);
    if (ll < 18) {                                            // n1: j = 32+ll (<= 49), compacted
        split8(Wl + (size_t)(32 + ll) * FW, kb, width, hi, lo);
        *reinterpret_cast<uint4*>(base + 2048 + (kh * 18 + ll) * 16) = make_uint4(hi[0], hi[1], hi[2], hi[3]);
        *reinterpret_cast<uint4*>(base + 2624 + (kh * 18 + ll) * 16) = make_uint4(lo[0], lo[1], lo[2], lo[3]);
    }
}

// B-fragment pair for one chunk; wb pre-offset by +2048 for n==1. Zeros past end.
__device__ __forceinline__ void loadB2(const char* __restrict__ wb, int ci, int chunks,
                                       int n, int l, int ll, int kh,
                                       bf16x8& bh, bf16x8& bl) {
    bf16x8 z = {0, 0, 0, 0, 0, 0, 0, 0};
    bh = z; bl = z;
    if (ci < chunks) {                       // wave-uniform
        const char* cb = wb + (size_t)ci * CHUNK_STRIDE;
        if (n == 0) {
            bh = *(const bf16x8*)(cb + l * 16);
            bl = *(const bf16x8*)(cb + 1024 + l * 16);
        } else if (ll < 18) {
            bh = *(const bf16x8*)(cb + (kh * 18 + ll) * 16);
            bl = *(const bf16x8*)(cb + 576 + (kh * 18 + ll) * 16);
        }
    }
}
// group = 2 chunks (ci, ci+4)
__device__ __forceinline__ void loadG2(const char* __restrict__ wb, int c0, int chunks,
                                       int n, int l, int ll, int kh,
                                       bf16x8& b0h, bf16x8& b0l, bf16x8& b1h, bf16x8& b1l) {
    loadB2(wb, c0,     chunks, n, l, ll, kh, b0h, b0l);
    loadB2(wb, c0 + 4, chunks, n, l, ll, kh, b1h, b1l);
}

// A-fragments + 3-term MFMA for one chunk; xrh/xrl pre-offset by ll*XSTR + kh*8
__device__ __forceinline__ void mfma3(const unsigned short* xrh, const unsigned short* xrl,
                                      int kof, const bf16x8 bh, const bf16x8 bl, f32x16& acc) {
    bf16x8 ah = *(const bf16x8*)(xrh + kof);
    bf16x8 al = *(const bf16x8*)(xrl + kof);
    acc = __builtin_amdgcn_mfma_f32_32x32x16_bf16(al, bh, acc, 0, 0, 0);
    acc = __builtin_amdgcn_mfma_f32_32x32x16_bf16(ah, bl, acc, 0, 0, 0);
    acc = __builtin_amdgcn_mfma_f32_32x32x16_bf16(ah, bh, acc, 0, 0, 0);
}

// ---------------- main kernel ----------------
__global__ __launch_bounds__(NTHREADS, 2) void densenet_mfma(
    const float* __restrict__ state, const char* __restrict__ wsbuf,
    const float* __restrict__ bs,    const float* __restrict__ Wout,
    const float* __restrict__ bout,  float* __restrict__ out)
{
    __shared__ __align__(16) char lds[LDS_BYTES];
    unsigned short* xhi = (unsigned short*)lds;
    unsigned short* xlo = (unsigned short*)(lds + XLO_OFF);
    float* slab  = (float*)(lds + SLAB_OFF);   // [kq 4][row 24][col 64]
    float* woutl = (float*)(lds + WOUT_OFF);
    float* biasl = (float*)(lds + BIAS_OFF);

    const int tid = threadIdx.x;
    const int w   = tid >> 6;
    const int l   = tid & 63;
    const int ll  = l & 31, kh = l >> 5;
    const int kq  = w & 3;          // K-chunk residue this wave owns
    const int n   = w >> 2;         // N-tile this wave owns
    const long row0 = (long)blockIdx.x * TR;

    // zero x planes (masks k-tails, dead batch rows, padded-group reads)
    {
        unsigned* p = (unsigned*)lds;
        for (int i = tid; i < (XLO_OFF * 2) / 4; i += NTHREADS) p[i] = 0u;
    }
    for (int i = tid; i < FW; i += NTHREADS)      woutl[i] = Wout[i];
    for (int i = tid; i < NL * KJ; i += NTHREADS) biasl[i] = bs[i];
    __syncthreads();
    if (tid < TR * IN) {
        int r = tid >> 4, c = tid & 15;
        if (row0 + r < BTOT) {
            float v = state[(row0 + r) * IN + c];
            float hif;
            xhi[r * XSTR + c] = bf16_hi(v, &hif);
            xlo[r * XSTR + c] = bf16_rnd(v - hif);
        }
    }
    __syncthreads();   // x init visible to all waves

    const unsigned short* xrh = xhi + ll * XSTR + (kh << 3);   // A-row base (rows 24..31:
    const unsigned short* xrl = xlo + ll * XSTR + (kh << 3);   // in-bounds garbage, dead regs)

    int width = IN;
    size_t wofs = 0;
    for (int layer = 0; layer < NL; ++layer) {
        const int chunks = (width + 15) >> 4;
        const char* wb = wsbuf + wofs + (n ? 2048 : 0);

        f32x16 a0, a1, a2, a3;
#pragma unroll
        for (int i = 0; i < 16; ++i) { a0[i] = 0.f; a1[i] = 0.f; a2[i] = 0.f; a3[i] = 0.f; }

        // t-slots: ci = kq + 4t, t < T. Groups of 2 t-slots; NG padded even.
        const int T  = (chunks > kq) ? ((chunks - kq + 3) >> 2) : 0;
        int NG = (T + 1) >> 1;
        NG += (NG & 1);

        if (NG > 0) {
            bf16x8 A0h, A0l, A1h, A1l, B0h, B0l, B1h, B1l;
            loadG2(wb, kq, chunks, n, l, ll, kh, A0h, A0l, A1h, A1l);
            for (int G = 0; G < NG; G += 2) {
                const int c0 = kq + (G << 3);
                loadG2(wb, c0 + 8, chunks, n, l, ll, kh, B0h, B0l, B1h, B1l);  // group G+1
                mfma3(xrh, xrl, (c0)     << 4, A0h, A0l, a0);
                mfma3(xrh, xrl, (c0 + 4) << 4, A1h, A1l, a1);
                if (G + 2 < NG)
                    loadG2(wb, c0 + 16, chunks, n, l, ll, kh, A0h, A0l, A1h, A1l);
                mfma3(xrh, xrl, (c0 + 8)  << 4, B0h, B0l, a2);
                mfma3(xrh, xrl, (c0 + 12) << 4, B1h, B1l, a3);
            }
        }

        // merge 4 chains; slab write: C col=l&31, row=(r&3)+8*(r>>2)+4*kh; col n*32+ll == j
        {
            float* sl = slab + kq * 1536;
#pragma unroll
            for (int r = 0; r < 12; ++r) {
                float v = (a0[r] + a1[r]) + (a2[r] + a3[r]);
                int crow = (r & 3) + 8 * (r >> 2) + 4 * kh;
                sl[crow * 64 + n * 32 + ll] = v;
            }
        }
        __syncthreads();   // (1) slab complete; all A-reads of this layer done

        // merged reduce: 24 rows x 64 cols, j<50 live
#pragma unroll
        for (int it = 0; it < 3; ++it) {
            int idx = it * NTHREADS + tid;
            int row = idx >> 6, j = idx & 63;
            float s = (slab[row * 64 + j] + slab[1536 + row * 64 + j])
                    + (slab[3072 + row * 64 + j] + slab[4608 + row * 64 + j]);
            if (j < KJ) {
                s += biasl[layer * KJ + j];
                s = (s > 0.f) ? s : 0.01f * s;
                float hif;
                xhi[row * XSTR + width + j] = bf16_hi(s, &hif);
                xlo[row * XSTR + width + j] = bf16_rnd(s - hif);
            }
        }
        __syncthreads();   // (2) new x cols visible; slab free

        width += KJ;
        wofs += (size_t)chunks * CHUNK_STRIDE;
    }

    // epilogue: out[r] = x[r] . Wout + bout ; 3 rows/wave; Wout from LDS
    const float b0 = bout[0];
#pragma unroll
    for (int rr = 0; rr < 3; ++rr) {
        const int row = w * 3 + rr;
        const long grow = row0 + row;
        const unsigned short* xh = xhi + row * XSTR;
        const unsigned short* xl = xlo + row * XSTR;
        float s = 0.f;
#pragma unroll
        for (int it = 0; it < 19; ++it) {   // 19*64 = 1216
            int k = l + (it << 6);
            float xv = __uint_as_float((unsigned)xh[k] << 16)
                     + __uint_as_float((unsigned)xl[k] << 16);
            s += xv * woutl[k];
        }
        {
            int k = 1216 + l;
            if (k < FW) {
                float xv = __uint_as_float((unsigned)xh[k] << 16)
                         + __uint_as_float((unsigned)xl[k] << 16);
                s += xv * woutl[k];
            }
        }
#pragma unroll
        for (int m = 32; m >= 1; m >>= 1) s += __shfl_xor(s, m, 64);
        if (l == 0 && grow < BTOT) out[grow] = s + b0;
    }
}

extern "C" void kernel_launch(void* const* d_in, const int* in_sizes, int n_in,
                              void* d_out, int out_size, void* d_ws, size_t ws_size,
                              hipStream_t stream) {
    const float* state = (const float*)d_in[0];
    const float* Ws    = (const float*)d_in[1];
    const float* bs    = (const float*)d_in[2];
    const float* Wout  = (const float*)d_in[3];
    const float* bout  = (const float*)d_in[4];
    float* out = (float*)d_out;
    char* wsbuf = (char*)d_ws;   // needs TOTAL_CHUNKS*CHUNK_STRIDE = 3,113,600 B

    split_w<<<dim3(TOTAL_CHUNKS), dim3(64), 0, stream>>>(Ws, wsbuf);
    densenet_mfma<<<dim3(NB), dim3(NTHREADS), 0, stream>>>(state, wsbuf, bs, Wout, bout, out);
}

// Round 8
// 500.473 us; speedup vs baseline: 1.1000x; 1.0237x over previous
//
#include <hip/hip_runtime.h>

// DenseNet ValueModel, bf16 3-term split MFMA, v6.
// vs v5 (512us, MfmaUtil 26%, Occupancy 21%): latency-bound at 2 waves/SIMD.
// v6: 1024-thread block (16 waves = 4 waves/SIMD, still 1 block/CU),
// K-split 8 x n-split 2, two-phase 8-deep slab reduction (4 barriers/layer),
// XSTR 1288->1272, bias in LDS, Wout direct-from-global epilogue.
// All MFMA chunk indices hard-guarded < chunks (wave-uniform): k-overrun
// stays inside the row stride; row-overrun (lanes 24..31) only pollutes dead
// C rows (acc regs 12..15). Pre-kernel byte-identical to PASSING v3/v4/v5.

#define IN 16
#define KJ 50
#define NL 25
#define FW 1266
#define TR 24
#define NB 1366          // ceil(32768/24); last block: 8 live rows
#define BTOT 32768
#define XSTR 1272        // u16/row (>= 1266, mult of 8)
#define NTHREADS 1024
#define XLO_OFF 61056    // 24*1272*2
#define SLAB_OFF 122112  // 2*61056
#define BIAS_OFF 154880  // + 8*16*64*4 slab (32768 B)
#define LDS_BYTES 159880 // + 1250*4 bias; <= 163840 -> 1 block/CU, 4 waves/SIMD
#define CHUNK_STRIDE 3200
#define TOTAL_CHUNKS 973

typedef __attribute__((ext_vector_type(8))) short bf16x8;
typedef __attribute__((ext_vector_type(16))) float f32x16;

__device__ __forceinline__ unsigned short bf16_hi(float x, float* hif) {
    unsigned u = __float_as_uint(x);
    unsigned h = (u + 0x8000u) >> 16;
    *hif = __uint_as_float(h << 16);
    return (unsigned short)h;
}
__device__ __forceinline__ unsigned short bf16_rnd(float x) {
    return (unsigned short)((__float_as_uint(x) + 0x8000u) >> 16);
}

// ---------------- pre-kernel: split + fragment W into d_ws (UNCHANGED, verified) ----
__device__ __forceinline__ void split8(const float* __restrict__ rowp, int kb, int width,
                                       unsigned hi[4], unsigned lo[4]) {
#pragma unroll
    for (int p = 0; p < 4; ++p) {
        unsigned h2[2], l2[2];
#pragma unroll
        for (int q = 0; q < 2; ++q) {
            int k = kb + p * 2 + q;
            float v = (k < width) ? rowp[k] : 0.f;
            float hif;
            unsigned short h = bf16_hi(v, &hif);
            h2[q] = h;
            l2[q] = bf16_rnd(v - hif);
        }
        hi[p] = h2[0] | (h2[1] << 16);
        lo[p] = l2[0] | (l2[1] << 16);
    }
}

__global__ __launch_bounds__(64, 1) void split_w(const float* __restrict__ Ws,
                                                 char* __restrict__ wsbuf) {
    int rem = blockIdx.x, layer = 0;
    size_t off = 0;
    for (;;) {
        int c = (IN + KJ * layer + 15) >> 4;
        if (rem < c) break;
        rem -= c; off += (size_t)c * CHUNK_STRIDE; ++layer;
    }
    const int ci = rem, k0 = ci << 4, width = IN + KJ * layer;
    const float* Wl = Ws + (size_t)layer * KJ * FW;
    char* base = wsbuf + off + (size_t)ci * CHUNK_STRIDE;
    const int l = threadIdx.x, ll = l & 31, kh = l >> 5;
    const int kb = k0 + kh * 8;

    unsigned hi[4], lo[4];
    split8(Wl + (size_t)ll * FW, kb, width, hi, lo);          // n0: j = ll (< 50)
    *reinterpret_cast<uint4*>(base + l * 16)        = make_uint4(hi[0], hi[1], hi[2], hi[3]);
    *reinterpret_cast<uint4*>(base + 1024 + l * 16) = make_uint4(lo[0], lo[1], lo[2], lo[3]);
    if (ll < 18) {                                            // n1: j = 32+ll (<= 49), compacted
        split8(Wl + (size_t)(32 + ll) * FW, kb, width, hi, lo);
        *reinterpret_cast<uint4*>(base + 2048 + (kh * 18 + ll) * 16) = make_uint4(hi[0], hi[1], hi[2], hi[3]);
        *reinterpret_cast<uint4*>(base + 2624 + (kh * 18 + ll) * 16) = make_uint4(lo[0], lo[1], lo[2], lo[3]);
    }
}

// B-fragment pair for one chunk; wb pre-offset by +2048 for n==1. Zeros past end.
__device__ __forceinline__ void loadB2(const char* __restrict__ wb, int ci, int chunks,
                                       int n, int l, int ll, int kh,
                                       bf16x8& bh, bf16x8& bl) {
    bf16x8 z = {0, 0, 0, 0, 0, 0, 0, 0};
    bh = z; bl = z;
    if (ci < chunks) {                       // wave-uniform
        const char* cb = wb + (size_t)ci * CHUNK_STRIDE;
        if (n == 0) {
            bh = *(const bf16x8*)(cb + l * 16);
            bl = *(const bf16x8*)(cb + 1024 + l * 16);
        } else if (ll < 18) {
            bh = *(const bf16x8*)(cb + (kh * 18 + ll) * 16);
            bl = *(const bf16x8*)(cb + 576 + (kh * 18 + ll) * 16);
        }
    }
}

// A-fragments + 3-term MFMA for one chunk; xrh/xrl pre-offset by ll*XSTR + kh*8
__device__ __forceinline__ void mfma3(const unsigned short* xrh, const unsigned short* xrl,
                                      int kof, const bf16x8 bh, const bf16x8 bl, f32x16& acc) {
    bf16x8 ah = *(const bf16x8*)(xrh + kof);
    bf16x8 al = *(const bf16x8*)(xrl + kof);
    acc = __builtin_amdgcn_mfma_f32_32x32x16_bf16(al, bh, acc, 0, 0, 0);
    acc = __builtin_amdgcn_mfma_f32_32x32x16_bf16(ah, bl, acc, 0, 0, 0);
    acc = __builtin_amdgcn_mfma_f32_32x32x16_bf16(ah, bh, acc, 0, 0, 0);
}

// ---------------- main kernel: 1024 threads, 16 waves ----------------
__global__ __launch_bounds__(NTHREADS, 4) void densenet_mfma(
    const float* __restrict__ state, const char* __restrict__ wsbuf,
    const float* __restrict__ bs,    const float* __restrict__ Wout,
    const float* __restrict__ bout,  float* __restrict__ out)
{
    __shared__ __align__(16) char lds[LDS_BYTES];
    unsigned short* xhi = (unsigned short*)lds;
    unsigned short* xlo = (unsigned short*)(lds + XLO_OFF);
    float* slab  = (float*)(lds + SLAB_OFF);   // h1: [q8][row16][col64]; h2: [q8][row8][col64]
    float* biasl = (float*)(lds + BIAS_OFF);

    const int tid = threadIdx.x;
    const int w   = tid >> 6;       // wave 0..15
    const int l   = tid & 63;
    const int ll  = l & 31, kh = l >> 5;
    const int kq  = w & 7;          // K-chunk residue this wave owns
    const int n   = w >> 3;         // N-tile this wave owns
    const long row0 = (long)blockIdx.x * TR;

    // zero x planes (masks k-tails, dead batch rows; cols >= width are zero
    // until their producing layer writes them)
    {
        unsigned* p = (unsigned*)lds;
        for (int i = tid; i < SLAB_OFF / 4; i += NTHREADS) p[i] = 0u;
    }
    for (int i = tid; i < NL * KJ; i += NTHREADS) biasl[i] = bs[i];
    __syncthreads();
    if (tid < TR * IN) {
        int r = tid >> 4, c = tid & 15;
        if (row0 + r < BTOT) {
            float v = state[(row0 + r) * IN + c];
            float hif;
            xhi[r * XSTR + c] = bf16_hi(v, &hif);
            xlo[r * XSTR + c] = bf16_rnd(v - hif);
        }
    }
    __syncthreads();   // x init visible to all waves

    const unsigned short* xrh = xhi + ll * XSTR + (kh << 3);   // A-row base (rows 24..31:
    const unsigned short* xrl = xlo + ll * XSTR + (kh << 3);   // in-LDS garbage, dead C rows)

    int width = IN;
    size_t wofs = 0;
    for (int layer = 0; layer < NL; ++layer) {
        const int chunks = (width + 15) >> 4;
        const char* wb = wsbuf + wofs + (n ? 2048 : 0);

        f32x16 a0, a1;
#pragma unroll
        for (int i = 0; i < 16; ++i) { a0[i] = 0.f; a1[i] = 0.f; }

        // wave (kq,n) owns chunks ci % 8 == kq; 2 chains, 2 named prefetch sets.
        // All mfma3 indices hard-guarded < chunks (wave-uniform) so A k-reads
        // stay inside the row stride (chunks*16 <= width+15 < XSTR).
        bf16x8 A0h, A0l, A1h, A1l, B0h, B0l, B1h, B1l;
        loadB2(wb, kq,     chunks, n, l, ll, kh, A0h, A0l);
        loadB2(wb, kq + 8, chunks, n, l, ll, kh, A1h, A1l);
        for (int c0 = kq; c0 < chunks; c0 += 32) {
            loadB2(wb, c0 + 16, chunks, n, l, ll, kh, B0h, B0l);
            loadB2(wb, c0 + 24, chunks, n, l, ll, kh, B1h, B1l);
            mfma3(xrh, xrl, c0 << 4, A0h, A0l, a0);
            if (c0 + 8 < chunks)  mfma3(xrh, xrl, (c0 + 8) << 4, A1h, A1l, a1);
            if (c0 + 32 < chunks) {
                loadB2(wb, c0 + 32, chunks, n, l, ll, kh, A0h, A0l);
                loadB2(wb, c0 + 40, chunks, n, l, ll, kh, A1h, A1l);
            }
            if (c0 + 16 < chunks) mfma3(xrh, xrl, (c0 + 16) << 4, B0h, B0l, a0);
            if (c0 + 24 < chunks) mfma3(xrh, xrl, (c0 + 24) << 4, B1h, B1l, a1);
        }

        // ---- phase h1: acc regs 0..7 <-> C rows 0..15 ----
        // C layout (verified): col = l&31, row = (r&3) + 8*(r>>2) + 4*kh
        {
            float* s1 = slab + kq * 1024 + n * 32 + ll;
#pragma unroll
            for (int r = 0; r < 8; ++r) {
                int crow = (r & 3) + 8 * (r >> 2) + 4 * kh;
                s1[crow * 64] = a0[r] + a1[r];
            }
        }
        __syncthreads();   // (1) h1 slab complete; all A-reads done
        {
            int row = tid >> 6, j = tid & 63;   // 16 x 64 == 1024: one elem/thread
            float s = 0.f;
#pragma unroll
            for (int q = 0; q < 8; ++q) s += slab[q * 1024 + row * 64 + j];
            if (j < KJ) {
                s += biasl[layer * KJ + j];
                s = (s > 0.f) ? s : 0.01f * s;
                float hif;
                xhi[row * XSTR + width + j] = bf16_hi(s, &hif);
                xlo[row * XSTR + width + j] = bf16_rnd(s - hif);
            }
        }
        __syncthreads();   // (2) h1 slab reads done -> region reusable
        // ---- phase h2: acc regs 8..11 <-> C rows 16..23 ----
        {
            float* s2 = slab + kq * 512 + n * 32 + ll;
#pragma unroll
            for (int r = 0; r < 4; ++r) {
                int lrow = (r & 3) + 4 * kh;    // 0..7 -> global rows 16..23
                s2[lrow * 64] = a0[8 + r] + a1[8 + r];
            }
        }
        __syncthreads();   // (3)
        if (tid < 512) {
            int lrow = tid >> 6, j = tid & 63;
            int row = 16 + lrow;
            float s = 0.f;
#pragma unroll
            for (int q = 0; q < 8; ++q) s += slab[q * 512 + lrow * 64 + j];
            if (j < KJ) {
                s += biasl[layer * KJ + j];
                s = (s > 0.f) ? s : 0.01f * s;
                float hif;
                xhi[row * XSTR + width + j] = bf16_hi(s, &hif);
                xlo[row * XSTR + width + j] = bf16_rnd(s - hif);
            }
        }
        __syncthreads();   // (4) new x cols visible; slab free

        width += KJ;
        wofs += (size_t)chunks * CHUNK_STRIDE;
    }

    // epilogue: out[r] = x[r] . Wout + bout ; rows 0..15 -> waves 0..15,
    // rows 16..23 -> waves 0..7 (second pass). Wout straight from global (L2-hot).
    const float b0 = bout[0];
#pragma unroll
    for (int rr = 0; rr < 2; ++rr) {
        if (rr == 1 && w >= 8) break;
        const int row = rr ? 16 + w : w;
        const long grow = row0 + row;
        const unsigned short* xh = xhi + row * XSTR;
        const unsigned short* xl = xlo + row * XSTR;
        float s = 0.f;
#pragma unroll
        for (int it = 0; it < 19; ++it) {   // 19*64 = 1216
            int k = l + (it << 6);
            float xv = __uint_as_float((unsigned)xh[k] << 16)
                     + __uint_as_float((unsigned)xl[k] << 16);
            s += xv * Wout[k];
        }
        {
            int k = 1216 + l;
            if (k < FW) {
                float xv = __uint_as_float((unsigned)xh[k] << 16)
                         + __uint_as_float((unsigned)xl[k] << 16);
                s += xv * Wout[k];
            }
        }
#pragma unroll
        for (int m = 32; m >= 1; m >>= 1) s += __shfl_xor(s, m, 64);
        if (l == 0 && grow < BTOT) out[grow] = s + b0;
    }
}

extern "C" void kernel_launch(void* const* d_in, const int* in_sizes, int n_in,
                              void* d_out, int out_size, void* d_ws, size_t ws_size,
                              hipStream_t stream) {
    const float* state = (const float*)d_in[0];
    const float* Ws    = (const float*)d_in[1];
    const float* bs    = (const float*)d_in[2];
    const float* Wout  = (const float*)d_in[3];
    const float* bout  = (const float*)d_in[4];
    float* out = (float*)d_out;
    char* wsbuf = (char*)d_ws;   // needs TOTAL_CHUNKS*CHUNK_STRIDE = 3,113,600 B

    split_w<<<dim3(TOTAL_CHUNKS), dim3(64), 0, stream>>>(Ws, wsbuf);
    densenet_mfma<<<dim3(NB), dim3(NTHREADS), 0, stream>>>(state, wsbuf, bs, Wout, bout, out);
}

// Round 9
// 488.249 us; speedup vs baseline: 1.1275x; 1.0250x over previous
//
#include <hip/hip_runtime.h>

// DenseNet ValueModel, bf16 3-term split MFMA, v7: cross-layer overlap.
// v3/v5/v6 all ~500-550us with nothing saturated (MFMA 23%, VALU 47%, LDS
// ~38%, HBM 0.3%) and 2x occupancy buying +2% -> wall = per-layer barrier
// phase chain. v7 issues layer i+1's "head" MFMAs (chunks < win_i>>4, legal
// before layer i's reduce writes cols >= win_i) BEFORE barrier(1), so the
// matrix pipe works through layer i's reduce phases. Tail (~4 chunks) stays
// serial. Two compile-time-named acc sets (even/odd layers). Pre-kernel and
// all fragment/reduce layouts byte-identical to PASSING v6.

#define IN 16
#define KJ 50
#define NL 25
#define FW 1266
#define TR 24
#define NB 1366          // ceil(32768/24); last block: 8 live rows
#define BTOT 32768
#define XSTR 1272        // u16/row (>= 1266, mult of 8)
#define NTHREADS 1024
#define XLO_OFF 61056    // 24*1272*2
#define SLAB_OFF 122112  // 2*61056
#define BIAS_OFF 154880  // + 8*16*64*4 slab (32768 B)
#define LDS_BYTES 159880 // + 1250*4 bias; <= 163840 -> 1 block/CU, 4 waves/SIMD
#define CHUNK_STRIDE 3200
#define TOTAL_CHUNKS 973

typedef __attribute__((ext_vector_type(8))) short bf16x8;
typedef __attribute__((ext_vector_type(16))) float f32x16;

__device__ __forceinline__ unsigned short bf16_hi(float x, float* hif) {
    unsigned u = __float_as_uint(x);
    unsigned h = (u + 0x8000u) >> 16;
    *hif = __uint_as_float(h << 16);
    return (unsigned short)h;
}
__device__ __forceinline__ unsigned short bf16_rnd(float x) {
    return (unsigned short)((__float_as_uint(x) + 0x8000u) >> 16);
}

// ---------------- pre-kernel: split + fragment W into d_ws (UNCHANGED, verified) ----
__device__ __forceinline__ void split8(const float* __restrict__ rowp, int kb, int width,
                                       unsigned hi[4], unsigned lo[4]) {
#pragma unroll
    for (int p = 0; p < 4; ++p) {
        unsigned h2[2], l2[2];
#pragma unroll
        for (int q = 0; q < 2; ++q) {
            int k = kb + p * 2 + q;
            float v = (k < width) ? rowp[k] : 0.f;
            float hif;
            unsigned short h = bf16_hi(v, &hif);
            h2[q] = h;
            l2[q] = bf16_rnd(v - hif);
        }
        hi[p] = h2[0] | (h2[1] << 16);
        lo[p] = l2[0] | (l2[1] << 16);
    }
}

__global__ __launch_bounds__(64, 1) void split_w(const float* __restrict__ Ws,
                                                 char* __restrict__ wsbuf) {
    int rem = blockIdx.x, layer = 0;
    size_t off = 0;
    for (;;) {
        int c = (IN + KJ * layer + 15) >> 4;
        if (rem < c) break;
        rem -= c; off += (size_t)c * CHUNK_STRIDE; ++layer;
    }
    const int ci = rem, k0 = ci << 4, width = IN + KJ * layer;
    const float* Wl = Ws + (size_t)layer * KJ * FW;
    char* base = wsbuf + off + (size_t)ci * CHUNK_STRIDE;
    const int l = threadIdx.x, ll = l & 31, kh = l >> 5;
    const int kb = k0 + kh * 8;

    unsigned hi[4], lo[4];
    split8(Wl + (size_t)ll * FW, kb, width, hi, lo);          // n0: j = ll (< 50)
    *reinterpret_cast<uint4*>(base + l * 16)        = make_uint4(hi[0], hi[1], hi[2], hi[3]);
    *reinterpret_cast<uint4*>(base + 1024 + l * 16) = make_uint4(lo[0], lo[1], lo[2], lo[3]);
    if (ll < 18) {                                            // n1: j = 32+ll (<= 49), compacted
        split8(Wl + (size_t)(32 + ll) * FW, kb, width, hi, lo);
        *reinterpret_cast<uint4*>(base + 2048 + (kh * 18 + ll) * 16) = make_uint4(hi[0], hi[1], hi[2], hi[3]);
        *reinterpret_cast<uint4*>(base + 2624 + (kh * 18 + ll) * 16) = make_uint4(lo[0], lo[1], lo[2], lo[3]);
    }
}

// B-fragment pair for one chunk; wb pre-offset by +2048 for n==1. Zeros past bound.
__device__ __forceinline__ void loadB2(const char* __restrict__ wb, int ci, int bound,
                                       int n, int l, int ll, int kh,
                                       bf16x8& bh, bf16x8& bl) {
    bf16x8 z = {0, 0, 0, 0, 0, 0, 0, 0};
    bh = z; bl = z;
    if (ci < bound) {                        // wave-uniform
        const char* cb = wb + (size_t)ci * CHUNK_STRIDE;
        if (n == 0) {
            bh = *(const bf16x8*)(cb + l * 16);
            bl = *(const bf16x8*)(cb + 1024 + l * 16);
        } else if (ll < 18) {
            bh = *(const bf16x8*)(cb + (kh * 18 + ll) * 16);
            bl = *(const bf16x8*)(cb + 576 + (kh * 18 + ll) * 16);
        }
    }
}

// A-fragments + 3-term MFMA for one chunk; xrh/xrl pre-offset by ll*XSTR + kh*8
__device__ __forceinline__ void mfma3(const unsigned short* xrh, const unsigned short* xrl,
                                      int kof, const bf16x8 bh, const bf16x8 bl, f32x16& acc) {
    bf16x8 ah = *(const bf16x8*)(xrh + kof);
    bf16x8 al = *(const bf16x8*)(xrl + kof);
    acc = __builtin_amdgcn_mfma_f32_32x32x16_bf16(al, bh, acc, 0, 0, 0);
    acc = __builtin_amdgcn_mfma_f32_32x32x16_bf16(ah, bl, acc, 0, 0, 0);
    acc = __builtin_amdgcn_mfma_f32_32x32x16_bf16(ah, bh, acc, 0, 0, 0);
}

// One layer: tail into CUR0, h1 slab, head(next) into NXT (pre-barrier overlap),
// then the two reduce phases. CUR/NXT are compile-time register names (rule #20).
#define BODY(CUR0, CUR1, NXT0, NXT1, LAST)                                      \
{                                                                               \
    const int chunks = (width + 15) >> 4;                                       \
    const char* wb = wsbuf + wofs + (n ? 2048 : 0);                             \
    /* tail of this layer (chunks >= bnd with residue kq) into CUR0 */          \
    {                                                                           \
        int ci = bnd + ((kq - bnd) & 7);                                        \
        for (; ci < chunks; ci += 8) {                                          \
            bf16x8 tbh, tbl;                                                    \
            loadB2(wb, ci, chunks, n, l, ll, kh, tbh, tbl);                     \
            mfma3(xrh, xrl, ci << 4, tbh, tbl, CUR0);                           \
        }                                                                       \
    }                                                                           \
    /* h1 slab write: C col=l&31, row=(r&3)+8*(r>>2)+4*kh; slab col n*32+ll */  \
    {                                                                           \
        float* s1 = slab + kq * 1024 + n * 32 + ll;                             \
        _Pragma("unroll")                                                       \
        for (int r = 0; r < 8; ++r) {                                           \
            int crow = (r & 3) + 8 * (r >> 2) + 4 * kh;                         \
            s1[crow * 64] = CUR0[r] + CUR1[r];                                  \
        }                                                                       \
    }                                                                           \
    /* head of next layer into NXT: chunks < hbnd read cols < win_i only, */    \
    /* disjoint from this layer's reduce output cols [win_i, win_i+50) */       \
    if (!LAST) {                                                                \
        _Pragma("unroll")                                                       \
        for (int z = 0; z < 16; ++z) { NXT0[z] = 0.f; NXT1[z] = 0.f; }          \
        const int hbnd = width >> 4;                                            \
        const char* nwb = wb + (size_t)chunks * CHUNK_STRIDE;                   \
        bf16x8 A0h, A0l, A1h, A1l;                                              \
        loadB2(nwb, kq,     hbnd, n, l, ll, kh, A0h, A0l);                      \
        loadB2(nwb, kq + 8, hbnd, n, l, ll, kh, A1h, A1l);                      \
        for (int c0 = kq; c0 < hbnd; c0 += 16) {                                \
            mfma3(xrh, xrl, c0 << 4, A0h, A0l, NXT0);                           \
            if (c0 + 16 < hbnd) loadB2(nwb, c0 + 16, hbnd, n, l, ll, kh, A0h, A0l); \
            if (c0 + 8 < hbnd)  mfma3(xrh, xrl, (c0 + 8) << 4, A1h, A1l, NXT1); \
            if (c0 + 24 < hbnd) loadB2(nwb, c0 + 24, hbnd, n, l, ll, kh, A1h, A1l); \
        }                                                                       \
    }                                                                           \
    __syncthreads();   /* (1) slab h1 + this layer's A-reads done */            \
    {   /* h1 reduce: rows 0..15, one elem/thread */                            \
        int row = tid >> 6, j = tid & 63;                                       \
        float s = 0.f;                                                          \
        _Pragma("unroll")                                                       \
        for (int q = 0; q < 8; ++q) s += slab[q * 1024 + row * 64 + j];         \
        if (j < KJ) {                                                           \
            s += biasl[lidx * KJ + j];                                          \
            s = (s > 0.f) ? s : 0.01f * s;                                      \
            float hif;                                                          \
            xhi[row * XSTR + width + j] = bf16_hi(s, &hif);                     \
            xlo[row * XSTR + width + j] = bf16_rnd(s - hif);                    \
        }                                                                       \
    }                                                                           \
    __syncthreads();   /* (2) h1 slab reads done -> region reusable */          \
    {   /* h2 slab write: rows 16..23 <-> acc regs 8..11 */                     \
        float* s2 = slab + kq * 512 + n * 32 + ll;                              \
        _Pragma("unroll")                                                       \
        for (int r = 0; r < 4; ++r) {                                           \
            int lrow = (r & 3) + 4 * kh;                                        \
            s2[lrow * 64] = CUR0[8 + r] + CUR1[8 + r];                          \
        }                                                                       \
    }                                                                           \
    __syncthreads();   /* (3) */                                                \
    if (tid < 512) {                                                            \
        int lrow = tid >> 6, j = tid & 63;                                      \
        int row = 16 + lrow;                                                    \
        float s = 0.f;                                                          \
        _Pragma("unroll")                                                       \
        for (int q = 0; q < 8; ++q) s += slab[q * 512 + lrow * 64 + j];         \
        if (j < KJ) {                                                           \
            s += biasl[lidx * KJ + j];                                          \
            s = (s > 0.f) ? s : 0.01f * s;                                      \
            float hif;                                                          \
            xhi[row * XSTR + width + j] = bf16_hi(s, &hif);                     \
            xlo[row * XSTR + width + j] = bf16_rnd(s - hif);                    \
        }                                                                       \
    }                                                                           \
    __syncthreads();   /* (4) new x cols visible; slab free */                  \
    bnd = width >> 4;                                                           \
    width += KJ;                                                                \
    wofs += (size_t)chunks * CHUNK_STRIDE;                                      \
    ++lidx;                                                                     \
}

// ---------------- main kernel: 1024 threads, 16 waves ----------------
__global__ __launch_bounds__(NTHREADS, 4) void densenet_mfma(
    const float* __restrict__ state, const char* __restrict__ wsbuf,
    const float* __restrict__ bs,    const float* __restrict__ Wout,
    const float* __restrict__ bout,  float* __restrict__ out)
{
    __shared__ __align__(16) char lds[LDS_BYTES];
    unsigned short* xhi = (unsigned short*)lds;
    unsigned short* xlo = (unsigned short*)(lds + XLO_OFF);
    float* slab  = (float*)(lds + SLAB_OFF);   // h1: [q8][row16][col64]; h2: [q8][row8][col64]
    float* biasl = (float*)(lds + BIAS_OFF);

    const int tid = threadIdx.x;
    const int w   = tid >> 6;       // wave 0..15
    const int l   = tid & 63;
    const int ll  = l & 31, kh = l >> 5;
    const int kq  = w & 7;          // K-chunk residue this wave owns
    const int n   = w >> 3;         // N-tile this wave owns
    const long row0 = (long)blockIdx.x * TR;

    // zero x planes (masks k-tails, dead batch rows; cols >= width stay zero
    // until their producing layer writes them)
    {
        unsigned* p = (unsigned*)lds;
        for (int i = tid; i < SLAB_OFF / 4; i += NTHREADS) p[i] = 0u;
    }
    for (int i = tid; i < NL * KJ; i += NTHREADS) biasl[i] = bs[i];
    __syncthreads();
    if (tid < TR * IN) {
        int r = tid >> 4, c = tid & 15;
        if (row0 + r < BTOT) {
            float v = state[(row0 + r) * IN + c];
            float hif;
            xhi[r * XSTR + c] = bf16_hi(v, &hif);
            xlo[r * XSTR + c] = bf16_rnd(v - hif);
        }
    }
    __syncthreads();   // x init visible to all waves

    const unsigned short* xrh = xhi + ll * XSTR + (kh << 3);   // A-row base (rows 24..31:
    const unsigned short* xrl = xlo + ll * XSTR + (kh << 3);   // in-LDS garbage, dead C rows)

    f32x16 cA0, cA1, nA0, nA1;
#pragma unroll
    for (int i = 0; i < 16; ++i) { cA0[i] = 0.f; cA1[i] = 0.f; nA0[i] = 0.f; nA1[i] = 0.f; }

    int lidx = 0, width = IN, bnd = 0;
    size_t wofs = 0;
    for (int ip = 0; ip < 12; ++ip) {
        BODY(cA0, cA1, nA0, nA1, 0)     // even layer
        BODY(nA0, nA1, cA0, cA1, 0)     // odd layer
    }
    BODY(cA0, cA1, nA0, nA1, 1)         // layer 24 (head(24) already in cA)

    // epilogue: out[r] = x[r] . Wout + bout ; rows 0..15 -> waves 0..15,
    // rows 16..23 -> waves 0..7 (second pass). Wout straight from global (L2-hot).
    const float b0 = bout[0];
#pragma unroll
    for (int rr = 0; rr < 2; ++rr) {
        if (rr == 1 && w >= 8) break;
        const int row = rr ? 16 + w : w;
        const long grow = row0 + row;
        const unsigned short* xh = xhi + row * XSTR;
        const unsigned short* xl = xlo + row * XSTR;
        float s = 0.f;
#pragma unroll
        for (int it = 0; it < 19; ++it) {   // 19*64 = 1216
            int k = l + (it << 6);
            float xv = __uint_as_float((unsigned)xh[k] << 16)
                     + __uint_as_float((unsigned)xl[k] << 16);
            s += xv * Wout[k];
        }
        {
            int k = 1216 + l;
            if (k < FW) {
                float xv = __uint_as_float((unsigned)xh[k] << 16)
                         + __uint_as_float((unsigned)xl[k] << 16);
                s += xv * Wout[k];
            }
        }
#pragma unroll
        for (int m = 32; m >= 1; m >>= 1) s += __shfl_xor(s, m, 64);
        if (l == 0 && grow < BTOT) out[grow] = s + b0;
    }
}

extern "C" void kernel_launch(void* const* d_in, const int* in_sizes, int n_in,
                              void* d_out, int out_size, void* d_ws, size_t ws_size,
                              hipStream_t stream) {
    const float* state = (const float*)d_in[0];
    const float* Ws    = (const float*)d_in[1];
    const float* bs    = (const float*)d_in[2];
    const float* Wout  = (const float*)d_in[3];
    const float* bout  = (const float*)d_in[4];
    float* out = (float*)d_out;
    char* wsbuf = (char*)d_ws;   // needs TOTAL_CHUNKS*CHUNK_STRIDE = 3,113,600 B

    split_w<<<dim3(TOTAL_CHUNKS), dim3(64), 0, stream>>>(Ws, wsbuf);
    densenet_mfma<<<dim3(NB), dim3(NTHREADS), 0, stream>>>(state, wsbuf, bs, Wout, bout, out);
}